// Round 14
// baseline (375.804 us; speedup 1.0000x reference)
//
#include <hip/hip_runtime.h>
#include <math.h>

#define NP 256   // datapoints
#define BB 128   // batch
#define DD 784   // dims
#define HS_MIN 1e-7f
#define LOG_HS_MIN -16.11809565095832f   // log(1e-7)
#define LOG_MB -16.811242831518264f      // log(5e-8) — mask bound in log space
#define NEG_HALF_LOG_2PI -0.9189385332046727f
#define W 8      // householder window
#define NW 98    // 784/8
#define TSTR 6400   // LDS tile stride (8*784=6272 rounded up to 25*256)

// ---------------- ndtri (AS241, double poly) from log_cdf / log_sf ----------------
__device__ double ndtri_logs(float log_cdf_f, float log_sf_f) {
    double lp = (double)log_cdf_f;
    double ls = (double)log_sf_f;
    double p = (double)__expf(log_cdf_f);
    double q = p - 0.5;
    if (fabs(q) <= 0.425) {
        double r = 0.180625 - q * q;
        double num = (((((((2.5090809287301226727e3 * r + 3.3430575583588128105e4) * r
                         + 6.7265770927008700853e4) * r + 4.5921953931549871457e4) * r
                         + 1.3731693765509461125e4) * r + 1.9715909503065514427e3) * r
                         + 1.3314166789178437745e2) * r + 3.3871328727963666080e0);
        double den = (((((((5.2264952788528545610e3 * r + 2.8729085735721942674e4) * r
                         + 3.9307895800092710610e4) * r + 2.1213794301586595867e4) * r
                         + 5.3941960214247511077e3) * r + 6.8718700749205790830e2) * r
                         + 4.2313330701600911252e1) * r + 1.0);
        return q * num / den;
    }
    // tail: r = sqrt(-log(min(p,1-p))) straight from the log — no 1-p cancellation
    double r = (q < 0.0) ? sqrt(-lp) : sqrt(-ls);
    double v;
    if (r <= 5.0) {
        r -= 1.6;
        double num = (((((((7.74545014278341407640e-4 * r + 2.27238449892691845833e-2) * r
                         + 2.41780725177450611770e-1) * r + 1.27045825245236838258e0) * r
                         + 3.64784832476320460504e0) * r + 5.76949722146069140550e0) * r
                         + 4.63033784615654529590e0) * r + 1.42343711074968357734e0);
        double den = (((((((1.05075007164441684324e-9 * r + 5.47593808499534494600e-4) * r
                         + 1.51986665636164571966e-2) * r + 1.48103976427480074590e-1) * r
                         + 6.89767334985100004550e-1) * r + 1.67638483018380384940e0) * r
                         + 2.05319162663775882187e0) * r + 1.0);
        v = num / den;
    } else {
        r -= 5.0;
        double num = (((((((2.01033439929228813265e-7 * r + 2.71155556874348757815e-5) * r
                         + 1.24266094738807843860e-3) * r + 2.65321895265761230930e-2) * r
                         + 2.96560571828504891230e-1) * r + 1.78482653991729133580e0) * r
                         + 5.46378491116411436990e0) * r + 6.65790464350110377720e0);
        double den = (((((((2.04426310338993978564e-15 * r + 1.42151175831644588870e-7) * r
                         + 1.84631831751005468180e-5) * r + 7.86869131145613259100e-4) * r
                         + 1.48753612908506148525e-2) * r + 1.36929880922735805310e-1) * r
                         + 5.99832206555887937690e-1) * r + 1.0);
        v = num / den;
    }
    return (q < 0.0) ? -v : v;
}

// ---------------- K0: lsew[d] = logsumexp_n kde_weights[n,d] (block per d) ----------------
__global__ __launch_bounds__(256) void k_lsew(const float* __restrict__ kw,
                                              float* __restrict__ lsew) {
    __shared__ float red[4];
    int d = blockIdx.x;
    int n = threadIdx.x;          // NP == 256 == blockDim
    float a = kw[n * DD + d];
    float m = a;
    #pragma unroll
    for (int off = 32; off; off >>= 1) m = fmaxf(m, __shfl_xor(m, off, 64));
    if ((threadIdx.x & 63) == 0) red[threadIdx.x >> 6] = m;
    __syncthreads();
    m = fmaxf(fmaxf(red[0], red[1]), fmaxf(red[2], red[3]));
    __syncthreads();
    float e = __expf(a - m);
    #pragma unroll
    for (int off = 32; off; off >>= 1) e += __shfl_xor(e, off, 64);
    if ((threadIdx.x & 63) == 0) red[threadIdx.x >> 6] = e;
    __syncthreads();
    if (threadIdx.x == 0)
        lsew[d] = m + __logf(red[0] + red[1] + red[2] + red[3]);
}

// ---------------- K1: per-(n,d) precompute, packed float4 {dp, 1/hs, w, w-lhc} ----------------
__global__ __launch_bounds__(256) void k_prep(const float* __restrict__ kw,
                                              const float* __restrict__ log_hs,
                                              const float* __restrict__ dp,
                                              const float* __restrict__ lsew,
                                              float4* __restrict__ pk) {
    int n = blockIdx.x;
    for (int d = threadIdx.x; d < DD; d += 256) {
        int idx = n * DD + d;
        float lh = log_hs[idx];
        float hs = fmaxf(__expf(lh), HS_MIN);
        float lhc = fmaxf(lh, LOG_HS_MIN);
        float wv = kw[idx] - lsew[d];
        pk[idx] = make_float4(dp[idx], 1.f / hs, wv, wv - lhc);
    }
}

// ---------------- K2: main KDE + inverse + term ----------------
__global__ __launch_bounds__(256) void k_main(const float* __restrict__ x,
                                              const float4* __restrict__ pk,
                                              float* __restrict__ Y,
                                              float* __restrict__ T) {
    unsigned t = blockIdx.x * 256u + threadIdx.x;   // t < B*D exactly
    unsigned b = t / DD;
    unsigned d = t - b * DD;
    float xv = x[t];
    float m1 = -INFINITY, s1 = 0.f;
    float m2 = -INFINITY, s2 = 0.f;
    float m3 = -INFINITY, s3 = 0.f;
    for (int n = 0; n < NP; ++n) {
        float4 c = pk[n * DD + d];          // {dp, ihs, w, w-lhc}
        float u = (c.x - xv) * c.y;
        float e = __expf(-fabsf(u));
        float l1p = __logf(1.f + e);
        float sp = fmaxf(u, 0.f) + l1p;
        float a1 = c.z - sp;
        float a2 = fminf(u, 0.f) - l1p + c.z;
        float a3 = u - 2.f * sp + c.w;
        float nm;
        nm = fmaxf(m1, a1); s1 = s1 * __expf(m1 - nm) + __expf(a1 - nm); m1 = nm;
        nm = fmaxf(m2, a2); s2 = s2 * __expf(m2 - nm) + __expf(a2 - nm); m2 = nm;
        nm = fmaxf(m3, a3); s3 = s3 * __expf(m3 - nm) + __expf(a3 - nm); m3 = nm;
    }
    float log_cdf = m1 + __logf(s1);
    float log_sf  = m2 + __logf(s2);
    float log_pdf = m3 + __logf(s3);

    // log-space mask classification (no f32 cancellation at cdf ~ 1)
    bool right = (log_sf  <= LOG_MB);
    bool left  = (log_cdf <= LOG_MB);

    float inv, lgd;
    if (right) {
        float t2 = -2.f * log_sf;
        inv = sqrtf(t2);
        lgd = 0.5f * __logf(t2) - log_sf;
    } else if (left) {
        float t2 = -2.f * log_cdf;
        inv = -sqrtf(t2);
        lgd = 0.5f * __logf(t2) - log_cdf;
    } else {
        inv = (float)ndtri_logs(log_cdf, log_sf);
        lgd = -0.5f * inv * inv + NEG_HALF_LOG_2PI;
    }
    Y[t] = inv;
    T[t] = log_pdf - lgd;
}

// ---------------- K3: log_det reduction ----------------
__global__ __launch_bounds__(256) void k_logdet(const float* __restrict__ T,
                                                const float* __restrict__ ld_in,
                                                float* __restrict__ out) {
    __shared__ float red[4];
    int b = blockIdx.x;
    float s = 0.f;
    for (int d = threadIdx.x; d < DD; d += 256) s += T[b * DD + d];
    #pragma unroll
    for (int off = 32; off; off >>= 1) s += __shfl_down(s, off, 64);
    if ((threadIdx.x & 63) == 0) red[threadIdx.x >> 6] = s;
    __syncthreads();
    if (threadIdx.x == 0) out[BB * DD + b] = ld_in[b] + red[0] + red[1] + red[2] + red[3];
}

// ---------------- K4: normalize reflector rows ----------------
__global__ __launch_bounds__(256) void k_vn(const float* __restrict__ vs,
                                            float* __restrict__ vn) {
    __shared__ float red[4];
    int i = blockIdx.x;
    float ss = 0.f;
    for (int j = threadIdx.x; j < DD; j += 256) {
        float v = vs[i * DD + j];
        ss += v * v;
    }
    #pragma unroll
    for (int off = 32; off; off >>= 1) ss += __shfl_down(ss, off, 64);
    if ((threadIdx.x & 63) == 0) red[threadIdx.x >> 6] = ss;
    __syncthreads();
    float inorm = rsqrtf(red[0] + red[1] + red[2] + red[3]);
    for (int j = threadIdx.x; j < DD; j += 256)
        vn[i * DD + j] = vs[i * DD + j] * inorm;
}

// ---------------- K5: Gram of each 8-reflector window (same math, W=8 blocks) ----------------
__global__ __launch_bounds__(64) void k_gram(const float* __restrict__ vn,
                                             float* __restrict__ G) {
    int wi = blockIdx.x;          // 0..97
    int t = threadIdx.x;          // 64 = 8x8
    int k = t >> 3, i = t & 7;
    const float4* a = (const float4*)(vn + (wi * W + k) * DD);
    const float4* b = (const float4*)(vn + (wi * W + i) * DD);
    float s = 0.f;
    for (int j = 0; j < DD / 4; ++j) {
        float4 av = a[j], bv = b[j];
        s += av.x * bv.x + av.y * bv.y + av.z * bv.z + av.w * bv.w;
    }
    G[wi * 64 + k * 8 + i] = s;   // G[w][k][i] = v_k . v_i
}

// ---------------- DPP wave64 sum: 6 VALU steps + readlane (no LDS pipe) ----------------
// Verified in rounds 10/11/13 (passed, absmax 1.0). Full 64-lane sum, wave-uniform.
__device__ __forceinline__ float wave_red_sum(float x) {
    x += __int_as_float(__builtin_amdgcn_update_dpp(0, __float_as_int(x), 0x111, 0xf, 0xf, true));
    x += __int_as_float(__builtin_amdgcn_update_dpp(0, __float_as_int(x), 0x112, 0xf, 0xf, true));
    x += __int_as_float(__builtin_amdgcn_update_dpp(0, __float_as_int(x), 0x114, 0xf, 0xf, true));
    x += __int_as_float(__builtin_amdgcn_update_dpp(0, __float_as_int(x), 0x118, 0xf, 0xf, true));
    x += __int_as_float(__builtin_amdgcn_update_dpp(0, __float_as_int(x), 0x142, 0xa, 0xf, true));
    x += __int_as_float(__builtin_amdgcn_update_dpp(0, __float_as_int(x), 0x143, 0xc, 0xf, true));
    return __int_as_float(__builtin_amdgcn_readlane(__float_as_int(x), 63));
}

// ---------------- K6: Householder chain — 4 waves/row, LDS-staged V (anti-remat final) ----------------
// Rounds 6/7/9/11/13 proved the allocator will NOT keep window-V live in VGPRs under
// any source structure (caps 32-160 regs, remats loads per phase with exposed L2
// waits). Fix: stop using registers for V. Stage window wi+1's tile into a TRIPLE-
// buffered LDS tile via global_load_lds at the top of window wi (drained for free by
// wi's own barrier, a full window later — not a fresh-prefetch drain), and read V
// from LDS in BOTH phases (re-read is ~free: conflict-free b32, consecutive lanes).
// Skeleton otherwise identical to verified round 13: DPP dots, lane0 publish,
// ONE barrier/window, redundant cross-wave sum + substitution + update.
// Triple-buffer safety (skew <= 1 window with 1 barrier/window): update(wi) reads
// buf[wi%3]; the furthest-ahead wave stages wi+2 into buf[(wi+2)%3] != buf[wi%3].
// red[] double-buffer safety as round 13. Math bit-identical to round 13.
__device__ __forceinline__ void stage_v(const float* __restrict__ VN, int wi,
                                        float* buf, int l, int wv) {
    const float* src = VN + (size_t)wi * (W * DD);
    // 25 chunks x 256 floats (last chunk over-reads 128 floats past the tile —
    // lands in the G region of the workspace, allocated; the pad is never read).
    for (int c = wv; c < 25; c += 4) {
        __builtin_amdgcn_global_load_lds(
            (const __attribute__((address_space(1))) void*)(src + c * 256 + l * 4),
            (__attribute__((address_space(3))) void*)(buf + c * 256),
            16, 0, 0);
    }
}

__global__ __launch_bounds__(256, 1) void k_house(const float* __restrict__ Yin,
                                                  const float* __restrict__ VN,
                                                  const float* __restrict__ G,
                                                  float* __restrict__ out) {
    __shared__ float vbuf[3][TSTR];       // 76800 B
    __shared__ float red[2][32];          // [buf][wave*8 + r]
    const int b = blockIdx.x;
    const int t = threadIdx.x;
    const int l = t & 63;
    const int wv = t >> 6;
    const int toff = 768 + (t & 15);      // clamped tail address (in-bounds all threads)
    const bool thas = (t < 16);

    float y0 = Yin[b * DD + t];
    float y1 = Yin[b * DD + t + 256];
    float y2 = Yin[b * DD + t + 512];
    float ytl = thas ? Yin[b * DD + toff] : 0.f;

    stage_v(VN, 0, vbuf[0], l, wv);
    __syncthreads();                      // drain window-0 staging

    for (int wi = 0; wi < NW; ++wi) {
        const float* bw = vbuf[wi % 3];
        const float* Gw = G + wi * 64;
        float* rb = &red[wi & 1][0];

        // prefetch next window while computing this one (drained by THIS window's barrier)
        if (wi + 1 < NW) stage_v(VN, wi + 1, vbuf[(wi + 1) % 3], l, wv);

        // dots from LDS: per-wave DPP sums (same values/order as round 13)
        float p[W];
        #pragma unroll
        for (int r = 0; r < W; ++r) {
            const float* vr = bw + r * DD;
            float v0 = vr[t];
            float v1 = vr[t + 256];
            float v2 = vr[t + 512];
            float vt = thas ? vr[toff] : 0.f;
            p[r] = wave_red_sum(y0 * v0 + y1 * v1 + y2 * v2 + ytl * vt);
        }

        // lane 0 of each wave publishes its 8 sums (two float4 LDS stores)
        if (l == 0) {
            *(float4*)&rb[wv * 8 + 0] = make_float4(p[0], p[1], p[2], p[3]);
            *(float4*)&rb[wv * 8 + 4] = make_float4(p[4], p[5], p[6], p[7]);
        }
        __syncthreads();

        // cross-wave sum (fixed order w=0..3), redundant on every thread (broadcast reads)
        float4 a0 = *(const float4*)&rb[0],  a1 = *(const float4*)&rb[4];
        float4 b0 = *(const float4*)&rb[8],  b1 = *(const float4*)&rb[12];
        float4 c0 = *(const float4*)&rb[16], c1 = *(const float4*)&rb[20];
        float4 d0 = *(const float4*)&rb[24], d1 = *(const float4*)&rb[28];
        float q[W];
        q[0] = a0.x + b0.x + c0.x + d0.x;
        q[1] = a0.y + b0.y + c0.y + d0.y;
        q[2] = a0.z + b0.z + c0.z + d0.z;
        q[3] = a0.w + b0.w + c0.w + d0.w;
        q[4] = a1.x + b1.x + c1.x + d1.x;
        q[5] = a1.y + b1.y + c1.y + d1.y;
        q[6] = a1.z + b1.z + c1.z + d1.z;
        q[7] = a1.w + b1.w + c1.w + d1.w;

        // forward substitution (same formula & association as verified rounds)
        float sv[W];
        #pragma unroll
        for (int r = 0; r < W; ++r) {
            float acc = q[r];
            #pragma unroll
            for (int k = 0; k < W; ++k)
                if (k < r) acc -= 2.f * Gw[k * 8 + r] * sv[k];
            sv[r] = acc;
        }

        // rank-8 update: re-read V from LDS (cheap, same bits as dot phase)
        #pragma unroll
        for (int r = 0; r < W; ++r) {
            const float* vr = bw + r * DD;
            float c = 2.f * sv[r];
            y0 -= c * vr[t];
            y1 -= c * vr[t + 256];
            y2 -= c * vr[t + 512];
            if (thas) ytl -= c * vr[toff];
        }
    }

    out[b * DD + t] = y0;
    out[b * DD + t + 256] = y1;
    out[b * DD + t + 512] = y2;
    if (thas)
        out[b * DD + toff] = ytl;
}

// ---------------- launch ----------------
extern "C" void kernel_launch(void* const* d_in, const int* in_sizes, int n_in,
                              void* d_out, int out_size, void* d_ws, size_t ws_size,
                              hipStream_t stream) {
    const float* x      = (const float*)d_in[0];   // [B,D]
    const float* ld_in  = (const float*)d_in[1];   // [B]
    const float* dp     = (const float*)d_in[2];   // [N,D]
    const float* log_hs = (const float*)d_in[3];   // [N,D]
    const float* kw     = (const float*)d_in[4];   // [N,D]
    const float* vs     = (const float*)d_in[5];   // [D,D]
    float* out = (float*)d_out;                    // x_out [B,D] then log_det [B]

    float* ws   = (float*)d_ws;
    float* lsew = ws;                         // 784 (pad to 1024)
    float4* pk  = (float4*)(ws + 1024);       // N*D float4
    float* Y    = ws + 1024 + NP * DD * 4;    // B*D
    float* T    = Y + BB * DD;                // B*D
    float* VN   = T + BB * DD;                // D*D
    float* G    = VN + DD * DD;               // NW*64 = 6272 (also absorbs stage over-read pad)

    k_lsew<<<DD, 256, 0, stream>>>(kw, lsew);
    k_prep<<<NP, 256, 0, stream>>>(kw, log_hs, dp, lsew, pk);
    k_main<<<(BB * DD) / 256, 256, 0, stream>>>(x, pk, Y, T);
    k_logdet<<<BB, 256, 0, stream>>>(T, ld_in, out);
    k_vn<<<DD, 256, 0, stream>>>(vs, VN);
    k_gram<<<NW, 64, 0, stream>>>(VN, G);
    k_house<<<BB, 256, 0, stream>>>(Y, VN, G, out);
}

// Round 15
// 289.091 us; speedup vs baseline: 1.2999x; 1.2999x over previous
//
#include <hip/hip_runtime.h>
#include <math.h>

#define NP 256   // datapoints
#define BB 128   // batch
#define DD 784   // dims
#define HS_MIN 1e-7f
#define LOG_HS_MIN -16.11809565095832f   // log(1e-7)
#define LOG_MB -16.811242831518264f      // log(5e-8) — mask bound in log space
#define NEG_HALF_LOG_2PI -0.9189385332046727f
#define W 8      // householder window
#define NW 98    // 784/8

// ---------------- ndtri (AS241, double poly) from log_cdf / log_sf ----------------
__device__ double ndtri_logs(float log_cdf_f, float log_sf_f) {
    double lp = (double)log_cdf_f;
    double ls = (double)log_sf_f;
    double p = (double)__expf(log_cdf_f);
    double q = p - 0.5;
    if (fabs(q) <= 0.425) {
        double r = 0.180625 - q * q;
        double num = (((((((2.5090809287301226727e3 * r + 3.3430575583588128105e4) * r
                         + 6.7265770927008700853e4) * r + 4.5921953931549871457e4) * r
                         + 1.3731693765509461125e4) * r + 1.9715909503065514427e3) * r
                         + 1.3314166789178437745e2) * r + 3.3871328727963666080e0);
        double den = (((((((5.2264952788528545610e3 * r + 2.8729085735721942674e4) * r
                         + 3.9307895800092710610e4) * r + 2.1213794301586595867e4) * r
                         + 5.3941960214247511077e3) * r + 6.8718700749205790830e2) * r
                         + 4.2313330701600911252e1) * r + 1.0);
        return q * num / den;
    }
    // tail: r = sqrt(-log(min(p,1-p))) straight from the log — no 1-p cancellation
    double r = (q < 0.0) ? sqrt(-lp) : sqrt(-ls);
    double v;
    if (r <= 5.0) {
        r -= 1.6;
        double num = (((((((7.74545014278341407640e-4 * r + 2.27238449892691845833e-2) * r
                         + 2.41780725177450611770e-1) * r + 1.27045825245236838258e0) * r
                         + 3.64784832476320460504e0) * r + 5.76949722146069140550e0) * r
                         + 4.63033784615654529590e0) * r + 1.42343711074968357734e0);
        double den = (((((((1.05075007164441684324e-9 * r + 5.47593808499534494600e-4) * r
                         + 1.51986665636164571966e-2) * r + 1.48103976427480074590e-1) * r
                         + 6.89767334985100004550e-1) * r + 1.67638483018380384940e0) * r
                         + 2.05319162663775882187e0) * r + 1.0);
        v = num / den;
    } else {
        r -= 5.0;
        double num = (((((((2.01033439929228813265e-7 * r + 2.71155556874348757815e-5) * r
                         + 1.24266094738807843860e-3) * r + 2.65321895265761230930e-2) * r
                         + 2.96560571828504891230e-1) * r + 1.78482653991729133580e0) * r
                         + 5.46378491116411436990e0) * r + 6.65790464350110377720e0);
        double den = (((((((2.04426310338993978564e-15 * r + 1.42151175831644588870e-7) * r
                         + 1.84631831751005468180e-5) * r + 7.86869131145613259100e-4) * r
                         + 1.48753612908506148525e-2) * r + 1.36929880922735805310e-1) * r
                         + 5.99832206555887937690e-1) * r + 1.0);
        v = num / den;
    }
    return (q < 0.0) ? -v : v;
}

// ---------------- K0: lsew[d] = logsumexp_n kde_weights[n,d] (block per d) ----------------
__global__ __launch_bounds__(256) void k_lsew(const float* __restrict__ kw,
                                              float* __restrict__ lsew) {
    __shared__ float red[4];
    int d = blockIdx.x;
    int n = threadIdx.x;          // NP == 256 == blockDim
    float a = kw[n * DD + d];
    float m = a;
    #pragma unroll
    for (int off = 32; off; off >>= 1) m = fmaxf(m, __shfl_xor(m, off, 64));
    if ((threadIdx.x & 63) == 0) red[threadIdx.x >> 6] = m;
    __syncthreads();
    m = fmaxf(fmaxf(red[0], red[1]), fmaxf(red[2], red[3]));
    __syncthreads();
    float e = __expf(a - m);
    #pragma unroll
    for (int off = 32; off; off >>= 1) e += __shfl_xor(e, off, 64);
    if ((threadIdx.x & 63) == 0) red[threadIdx.x >> 6] = e;
    __syncthreads();
    if (threadIdx.x == 0)
        lsew[d] = m + __logf(red[0] + red[1] + red[2] + red[3]);
}

// ---------------- K1: per-(n,d) precompute, packed float4 {dp, 1/hs, w, w-lhc} ----------------
__global__ __launch_bounds__(256) void k_prep(const float* __restrict__ kw,
                                              const float* __restrict__ log_hs,
                                              const float* __restrict__ dp,
                                              const float* __restrict__ lsew,
                                              float4* __restrict__ pk) {
    int n = blockIdx.x;
    for (int d = threadIdx.x; d < DD; d += 256) {
        int idx = n * DD + d;
        float lh = log_hs[idx];
        float hs = fmaxf(__expf(lh), HS_MIN);
        float lhc = fmaxf(lh, LOG_HS_MIN);
        float wv = kw[idx] - lsew[d];
        pk[idx] = make_float4(dp[idx], 1.f / hs, wv, wv - lhc);
    }
}

// ---------------- K2: main KDE + inverse + term ----------------
__global__ __launch_bounds__(256) void k_main(const float* __restrict__ x,
                                              const float4* __restrict__ pk,
                                              float* __restrict__ Y,
                                              float* __restrict__ T) {
    unsigned t = blockIdx.x * 256u + threadIdx.x;   // t < B*D exactly
    unsigned b = t / DD;
    unsigned d = t - b * DD;
    float xv = x[t];
    float m1 = -INFINITY, s1 = 0.f;
    float m2 = -INFINITY, s2 = 0.f;
    float m3 = -INFINITY, s3 = 0.f;
    for (int n = 0; n < NP; ++n) {
        float4 c = pk[n * DD + d];          // {dp, ihs, w, w-lhc}
        float u = (c.x - xv) * c.y;
        float e = __expf(-fabsf(u));
        float l1p = __logf(1.f + e);
        float sp = fmaxf(u, 0.f) + l1p;
        float a1 = c.z - sp;
        float a2 = fminf(u, 0.f) - l1p + c.z;
        float a3 = u - 2.f * sp + c.w;
        float nm;
        nm = fmaxf(m1, a1); s1 = s1 * __expf(m1 - nm) + __expf(a1 - nm); m1 = nm;
        nm = fmaxf(m2, a2); s2 = s2 * __expf(m2 - nm) + __expf(a2 - nm); m2 = nm;
        nm = fmaxf(m3, a3); s3 = s3 * __expf(m3 - nm) + __expf(a3 - nm); m3 = nm;
    }
    float log_cdf = m1 + __logf(s1);
    float log_sf  = m2 + __logf(s2);
    float log_pdf = m3 + __logf(s3);

    // log-space mask classification (no f32 cancellation at cdf ~ 1)
    bool right = (log_sf  <= LOG_MB);
    bool left  = (log_cdf <= LOG_MB);

    float inv, lgd;
    if (right) {
        float t2 = -2.f * log_sf;
        inv = sqrtf(t2);
        lgd = 0.5f * __logf(t2) - log_sf;
    } else if (left) {
        float t2 = -2.f * log_cdf;
        inv = -sqrtf(t2);
        lgd = 0.5f * __logf(t2) - log_cdf;
    } else {
        inv = (float)ndtri_logs(log_cdf, log_sf);
        lgd = -0.5f * inv * inv + NEG_HALF_LOG_2PI;
    }
    Y[t] = inv;
    T[t] = log_pdf - lgd;
}

// ---------------- K3: log_det reduction ----------------
__global__ __launch_bounds__(256) void k_logdet(const float* __restrict__ T,
                                                const float* __restrict__ ld_in,
                                                float* __restrict__ out) {
    __shared__ float red[4];
    int b = blockIdx.x;
    float s = 0.f;
    for (int d = threadIdx.x; d < DD; d += 256) s += T[b * DD + d];
    #pragma unroll
    for (int off = 32; off; off >>= 1) s += __shfl_down(s, off, 64);
    if ((threadIdx.x & 63) == 0) red[threadIdx.x >> 6] = s;
    __syncthreads();
    if (threadIdx.x == 0) out[BB * DD + b] = ld_in[b] + red[0] + red[1] + red[2] + red[3];
}

// ---------------- K4: normalize reflector rows ----------------
__global__ __launch_bounds__(256) void k_vn(const float* __restrict__ vs,
                                            float* __restrict__ vn) {
    __shared__ float red[4];
    int i = blockIdx.x;
    float ss = 0.f;
    for (int j = threadIdx.x; j < DD; j += 256) {
        float v = vs[i * DD + j];
        ss += v * v;
    }
    #pragma unroll
    for (int off = 32; off; off >>= 1) ss += __shfl_down(ss, off, 64);
    if ((threadIdx.x & 63) == 0) red[threadIdx.x >> 6] = ss;
    __syncthreads();
    float inorm = rsqrtf(red[0] + red[1] + red[2] + red[3]);
    for (int j = threadIdx.x; j < DD; j += 256)
        vn[i * DD + j] = vs[i * DD + j] * inorm;
}

// ---------------- K5: Gram of each 8-reflector window (same math, W=8 blocks) ----------------
__global__ __launch_bounds__(64) void k_gram(const float* __restrict__ vn,
                                             float* __restrict__ G) {
    int wi = blockIdx.x;          // 0..97
    int t = threadIdx.x;          // 64 = 8x8
    int k = t >> 3, i = t & 7;
    const float4* a = (const float4*)(vn + (wi * W + k) * DD);
    const float4* b = (const float4*)(vn + (wi * W + i) * DD);
    float s = 0.f;
    for (int j = 0; j < DD / 4; ++j) {
        float4 av = a[j], bv = b[j];
        s += av.x * bv.x + av.y * bv.y + av.z * bv.z + av.w * bv.w;
    }
    G[wi * 64 + k * 8 + i] = s;   // G[w][k][i] = v_k . v_i
}

// ---------------- DPP wave64 sum: 6 VALU steps + readlane (no LDS pipe) ----------------
// Verified rounds 10/11/13/14 (passed, absmax 1.0). Full 64-lane sum, wave-uniform.
__device__ __forceinline__ float wave_red_sum(float x) {
    x += __int_as_float(__builtin_amdgcn_update_dpp(0, __float_as_int(x), 0x111, 0xf, 0xf, true));
    x += __int_as_float(__builtin_amdgcn_update_dpp(0, __float_as_int(x), 0x112, 0xf, 0xf, true));
    x += __int_as_float(__builtin_amdgcn_update_dpp(0, __float_as_int(x), 0x114, 0xf, 0xf, true));
    x += __int_as_float(__builtin_amdgcn_update_dpp(0, __float_as_int(x), 0x118, 0xf, 0xf, true));
    x += __int_as_float(__builtin_amdgcn_update_dpp(0, __float_as_int(x), 0x142, 0xa, 0xf, true));
    x += __int_as_float(__builtin_amdgcn_update_dpp(0, __float_as_int(x), 0x143, 0xc, 0xf, true));
    return __int_as_float(__builtin_amdgcn_readlane(__float_as_int(x), 63));
}

// ---------------- K6: Householder chain — round-10 (best, 177us) + G in LDS ----------------
// Diagnosis: wall time = latency of ONE row's 98-window serial chain (all 128 rows run
// concurrently), so only the per-window critical path matters. The un-modeled ~3k
// cy/window across ALL variants (incl. round 7's held double-buffer that inexplicably
// didn't help) is the per-window G load from GLOBAL memory: issued after the V loads,
// waiting for it forces vmcnt(0) — draining the entire V pipeline every window.
// Fix (ONE variable vs round 10): stage ALL of G (98x64 floats = 25 KB) into LDS once
// at kernel start (~2us, once per block). Substitution then reads G via ds_read
// (lgkmcnt — separate counter), so no window ever drains the global-load pipeline
// for G again. Everything else is bit-identical to the verified round-10 kernel.
__global__ __launch_bounds__(64, 1) void k_house(const float* __restrict__ Yin,
                                                 const float* __restrict__ VN,
                                                 const float* __restrict__ G,
                                                 float* __restrict__ out) {
    __shared__ float gld[NW * 64];        // 25088 B: entire G table, staged once
    const int b = blockIdx.x;
    const int l = threadIdx.x;
    const int toff = 768 + (l & 15);      // clamped tail address (in-bounds all lanes)
    const bool thas = (l < 16);

    // one-time G stage: 98 coalesced dword loads per lane-stripe
    for (int i = l; i < NW * 64; i += 64) gld[i] = G[i];
    __syncthreads();

    float4 y[3];
    float ytl;
    #pragma unroll
    for (int i = 0; i < 3; ++i)
        y[i] = *(const float4*)(Yin + b * DD + 256 * i + 4 * l);
    ytl = thas ? Yin[b * DD + toff] : 0.f;

    for (int wi = 0; wi < NW; ++wi) {
        const float* Vw = VN + (size_t)wi * (W * DD);
        const float* Gw = gld + wi * 64;  // LDS: substitution never touches vmcnt

        // window's 8 V rows: 3 float4 + 1 tail scalar per lane (104 floats)
        float4 v[W][3];
        float vt[W];
        #pragma unroll
        for (int r = 0; r < W; ++r) {
            const float* vr = Vw + r * DD;
            #pragma unroll
            for (int i = 0; i < 3; ++i)
                v[r][i] = *(const float4*)(vr + 256 * i + 4 * l);
            vt[r] = thas ? vr[toff] : 0.f;
        }

        // raw dots q_r = y . v_r; DPP tree gives the full sum broadcast wave-uniform
        float p[W];
        #pragma unroll
        for (int r = 0; r < W; ++r) {
            float s = 0.f;
            #pragma unroll
            for (int i = 0; i < 3; ++i) {
                s += y[i].x * v[r][i].x + y[i].y * v[r][i].y
                   + y[i].z * v[r][i].z + y[i].w * v[r][i].w;
            }
            s += ytl * vt[r];                 // 0 on lanes >= 16
            p[r] = wave_red_sum(s);
        }

        // forward substitution (same formula & association as verified rounds), G from LDS
        float sv[W];
        #pragma unroll
        for (int r = 0; r < W; ++r) {
            float acc = p[r];
            #pragma unroll
            for (int k = 0; k < W; ++k)
                if (k < r) acc -= 2.f * Gw[k * 8 + r] * sv[k];
            sv[r] = acc;
        }

        // rank-8 update from the register copy of V
        #pragma unroll
        for (int r = 0; r < W; ++r) {
            float c = 2.f * sv[r];
            #pragma unroll
            for (int i = 0; i < 3; ++i) {
                y[i].x -= c * v[r][i].x;  y[i].y -= c * v[r][i].y;
                y[i].z -= c * v[r][i].z;  y[i].w -= c * v[r][i].w;
            }
            ytl -= c * vt[r];                 // stays 0 on lanes >= 16
        }
    }

    #pragma unroll
    for (int i = 0; i < 3; ++i)
        *(float4*)(out + b * DD + 256 * i + 4 * l) = y[i];
    if (thas)
        out[b * DD + toff] = ytl;
}

// ---------------- launch ----------------
extern "C" void kernel_launch(void* const* d_in, const int* in_sizes, int n_in,
                              void* d_out, int out_size, void* d_ws, size_t ws_size,
                              hipStream_t stream) {
    const float* x      = (const float*)d_in[0];   // [B,D]
    const float* ld_in  = (const float*)d_in[1];   // [B]
    const float* dp     = (const float*)d_in[2];   // [N,D]
    const float* log_hs = (const float*)d_in[3];   // [N,D]
    const float* kw     = (const float*)d_in[4];   // [N,D]
    const float* vs     = (const float*)d_in[5];   // [D,D]
    float* out = (float*)d_out;                    // x_out [B,D] then log_det [B]

    float* ws   = (float*)d_ws;
    float* lsew = ws;                         // 784 (pad to 1024)
    float4* pk  = (float4*)(ws + 1024);       // N*D float4
    float* Y    = ws + 1024 + NP * DD * 4;    // B*D
    float* T    = Y + BB * DD;                // B*D
    float* VN   = T + BB * DD;                // D*D
    float* G    = VN + DD * DD;               // NW*64 = 6272

    k_lsew<<<DD, 256, 0, stream>>>(kw, lsew);
    k_prep<<<NP, 256, 0, stream>>>(kw, log_hs, dp, lsew, pk);
    k_main<<<(BB * DD) / 256, 256, 0, stream>>>(x, pk, Y, T);
    k_logdet<<<BB, 256, 0, stream>>>(T, ld_in, out);
    k_vn<<<DD, 256, 0, stream>>>(vs, VN);
    k_gram<<<NW, 64, 0, stream>>>(VN, G);
    k_house<<<BB, 64, 0, stream>>>(Y, VN, G, out);
}